// Round 1
// baseline (272.291 us; speedup 1.0000x reference)
//
#include <hip/hip_runtime.h>

// out[rows[e], :] += edge_vals[e] * x[cols[e], :]
// One 64-lane wave per edge; lane = feature index (D_FEAT == 64).

#define D_FEAT 64

__global__ void spmv_coo_kernel(const float* __restrict__ x,
                                const int* __restrict__ rows,
                                const int* __restrict__ cols,
                                const float* __restrict__ ev,
                                float* __restrict__ out,
                                int n_edges) {
    const int lane = threadIdx.x & 63;
    const int wave_in_block = threadIdx.x >> 6;
    const int waves_per_block = blockDim.x >> 6;
    const int wave_global = blockIdx.x * waves_per_block + wave_in_block;
    const int n_waves = gridDim.x * waves_per_block;

    for (int e = wave_global; e < n_edges; e += n_waves) {
        const int r = rows[e];      // broadcast load (same addr across lanes)
        const int c = cols[e];
        const float v = ev[e];
        const float xv = x[c * D_FEAT + lane];   // coalesced 256B gather
        atomicAdd(&out[r * D_FEAT + lane], v * xv);  // coalesced scatter-add
    }
}

extern "C" void kernel_launch(void* const* d_in, const int* in_sizes, int n_in,
                              void* d_out, int out_size, void* d_ws, size_t ws_size,
                              hipStream_t stream) {
    // inputs: [0]=t (scalar), [1]=x [N,64] f32, [2]=rows [E] i32,
    //         [3]=cols [E] i32, [4]=edge_vals [E] f32
    const float* x    = (const float*)d_in[1];
    const int*   rows = (const int*)d_in[2];
    const int*   cols = (const int*)d_in[3];
    const float* ev   = (const float*)d_in[4];
    float* out = (float*)d_out;
    const int n_edges = in_sizes[3];

    // Harness poisons d_out with 0xAA and does NOT re-poison between replays:
    // we must zero it ourselves every call.
    hipMemsetAsync(d_out, 0, (size_t)out_size * sizeof(float), stream);

    const int block = 256;                 // 4 waves/block
    const int waves_wanted = 16384;        // grid-stride; ~76 edges/wave
    const int grid = waves_wanted / (block / 64);
    spmv_coo_kernel<<<grid, block, 0, stream>>>(x, rows, cols, ev, out, n_edges);
}